// Round 1
// baseline (86.083 us; speedup 1.0000x reference)
//
#include <hip/hip_runtime.h>

#define BB 2
#define HH 32
#define WW 32
#define CC 3
#define FF 16
#define M_PER_B (HH*WW*CC)        // 3072
#define N_PER_B (HH*WW*FF)        // 16384
#define CHN 256                   // n-chunk per block (LDS resident)
#define NQUADS (CHN/4)            // 64
#define NCHUNKS (N_PER_B / CHN)   // 64
#define MPT 2                     // m values per thread
#define MBLOCKS (M_PER_B / (256*MPT))  // 6

// difference[b,m] = sum_n tanh(x_m - y_n),  y = blurred = conv(x, g)
// tanh(d) = 1 - 2/(1+e^{2d});  e^{2x-2y} = E_m * F_n, E=e^{2x}, F=e^{-2y}
// => difference = N - 2*sum_n 1/(1 + E*F_n)
// Quad combine via elementary symmetric polynomials of {f0..f3} (shared
// across all m, precomputed in LDS):
//   sum_{i<4} 1/(1+E f_i) = N(E)/D(E)
//   D = 1 + e1 E + e2 E^2 + e3 E^3 + e4 E^4   (= prod(1+E f_i), all terms >0)
//   N = 4 + 3e1 E + 2e2 E^2 + e3 E^3
// Overflow: factors <= 1+e^16 => D <= ~6e27 << 3.4e38. No cancellation.
// (Octic merge would halve LDS reads but D8 can reach e^144 -> inf. Quads max.)
//
// REDUCTION CHANGE (this round): no atomics. Each (mb,nc,b) block stores its
// partial -2*sum into part[nc][b][m] (plain coalesced stores; every slot is
// fully written each launch, so the harness 0xAA ws-poison is never read).
// out_kernel reduces the 64 nc-partials for the <=300 difference values its
// tile needs into LDS, then convolves from LDS. This removes 393K
// device-scope atomicAdds that had 64-way same-address contention on a
// 24 KB (96-cacheline) target.
__global__ __launch_bounds__(256) void diff_kernel(
    const float* __restrict__ x,     // [B,H,W,C]
    const float* __restrict__ gk,    // [5,5,C,F]
    float* __restrict__ part)        // [NCHUNKS][B][M_PER_B] partials
{
    __shared__ float Fs[CHN];                    // e^{-2 y} per n
    __shared__ __align__(16) float Es[NQUADS*8]; // e1,e2,e3,e4,3e1,2e2,-,- per quad
    const int tid = threadIdx.x;
    const int b   = blockIdx.z;
    const int mb  = blockIdx.x;
    const int nc  = blockIdx.y;

    // E for this thread's two m values (overlaps the staging below)
    const int m0 = mb * (256*MPT) + tid;
    const int m1 = m0 + 256;
    const float E0 = __expf(2.0f * x[b*M_PER_B + m0]);
    const float E1 = __expf(2.0f * x[b*M_PER_B + m1]);

    // --- recompute this block's y chunk: blurred[b, nc*CHN + tid] ---
    {
        int n = nc * CHN + tid;
        int p = n >> 9;              // n / (W*F), W*F = 512
        int r = n & 511;
        int q = r >> 4;              // / F
        int f = r & 15;
        float acc = 0.f;
        #pragma unroll
        for (int dh = 0; dh < 5; ++dh) {
            int hh = p + dh - 2;
            if ((unsigned)hh >= (unsigned)HH) continue;
            #pragma unroll
            for (int dw = 0; dw < 5; ++dw) {
                int ww = q + dw - 2;
                if ((unsigned)ww >= (unsigned)WW) continue;
                const float* xin = x  + ((b*HH + hh)*WW + ww)*CC;
                const float* gg  = gk + ((dh*5 + dw)*CC)*FF + f;
                #pragma unroll
                for (int c = 0; c < CC; ++c)
                    acc += xin[c] * gg[c*FF];
            }
        }
        Fs[tid] = __expf(-2.0f * acc);
    }
    __syncthreads();

    // --- per-quad elementary symmetric polys (shared across m) ---
    if (tid < NQUADS) {
        float f0 = Fs[4*tid+0], f1 = Fs[4*tid+1];
        float f2 = Fs[4*tid+2], f3 = Fs[4*tid+3];
        float s01 = f0 + f1, s23 = f2 + f3;
        float p01 = f0 * f1, p23 = f2 * f3;
        float e1 = s01 + s23;
        float e2 = p01 + p23 + s01 * s23;
        float e3 = p01 * s23 + p23 * s01;
        float e4 = p01 * p23;
        float* e = &Es[8*tid];
        e[0] = e1; e[1] = e2; e[2] = e3; e[3] = e4;
        e[4] = 3.0f * e1; e[5] = 2.0f * e2;
    }
    __syncthreads();

    // --- hot loop: 1 quad x 2 m = 8 terms / iter; 16 fma + 2 rcp ---
    float s0 = 0.f, s1 = 0.f;
    #pragma unroll 4
    for (int q = 0; q < NQUADS; ++q) {
        const float4 d  = *(const float4*)(&Es[8*q]);    // e1 e2 e3 e4
        const float2 nv = *(const float2*)(&Es[8*q+4]);  // 3e1 2e2
        float num0 = fmaf(fmaf(fmaf(d.z, E0, nv.y), E0, nv.x), E0, 4.0f);
        float den0 = fmaf(fmaf(fmaf(fmaf(d.w, E0, d.z), E0, d.y), E0, d.x), E0, 1.0f);
        s0 = fmaf(num0, __builtin_amdgcn_rcpf(den0), s0);
        float num1 = fmaf(fmaf(fmaf(d.z, E1, nv.y), E1, nv.x), E1, 4.0f);
        float den1 = fmaf(fmaf(fmaf(fmaf(d.w, E1, d.z), E1, d.y), E1, d.x), E1, 1.0f);
        s1 = fmaf(num1, __builtin_amdgcn_rcpf(den1), s1);
    }
    // plain coalesced stores: this block exclusively owns part[nc][b][m0..]
    float* p = part + ((size_t)nc * BB + b) * M_PER_B;
    p[m0] = -2.0f * s0;
    p[m1] = -2.0f * s1;
}

// out[b,i,j,f] = conv(x, mker) - conv(difference, wker)
// difference[b,h,w,c] = 16384 + sum_nc part[nc][b,h,w,c]
// One block = (b, row i, j-half): 16 j x 16 f = 256 threads.
// Stage the 5x20x3 difference halo in LDS (reducing 64 partials per value).
__global__ __launch_bounds__(256) void out_kernel(
    const float* __restrict__ x,
    const float* __restrict__ mker,
    const float* __restrict__ wker,
    const float* __restrict__ part,   // [NCHUNKS][B][M_PER_B]
    float* __restrict__ out)
{
    __shared__ float dlds[5*20*3];     // [dh][dj][c], dj = ww-(j0-2)
    const int blk = blockIdx.x;        // b*64 + i*2 + jh
    const int tid = threadIdx.x;
    const int jh = blk & 1;
    const int i  = (blk >> 1) & 31;
    const int b  = blk >> 6;
    const int j0 = jh * 16;

    // --- reduce partials for the halo: 300 values, 64 partials each ---
    for (int v = tid; v < 5*20*3; v += 256) {
        int c  = v % 3;
        int t  = v / 3;          // 0..99
        int dj = t % 20;
        int dh = t / 20;         // 0..4
        int hh = i + dh - 2;
        int ww = j0 + dj - 2;
        float val = 0.f;
        if ((unsigned)hh < (unsigned)HH && (unsigned)ww < (unsigned)WW) {
            int m = (hh*WW + ww)*CC + c;
            const float* p = part + (size_t)b * M_PER_B + m;
            const int stride = BB * M_PER_B;    // floats between nc slices
            float a0 = 0.f, a1 = 0.f, a2 = 0.f, a3 = 0.f;
            #pragma unroll 4
            for (int nc = 0; nc < NCHUNKS; nc += 4) {
                a0 += p[(size_t)(nc+0) * stride];
                a1 += p[(size_t)(nc+1) * stride];
                a2 += p[(size_t)(nc+2) * stride];
                a3 += p[(size_t)(nc+3) * stride];
            }
            val = 16384.0f + ((a0 + a1) + (a2 + a3));
        }
        dlds[v] = val;
    }
    __syncthreads();

    const int f  = tid & 15;
    const int jj = tid >> 4;       // 0..15
    const int j  = j0 + jj;
    float ft = 0.f, st = 0.f;
    #pragma unroll
    for (int dh = 0; dh < 5; ++dh) {
        int hh = i + dh - 2;
        if ((unsigned)hh >= (unsigned)HH) continue;
        #pragma unroll
        for (int dw = 0; dw < 5; ++dw) {
            int ww = j + dw - 2;
            if ((unsigned)ww >= (unsigned)WW) continue;
            int base = ((b*HH + hh)*WW + ww)*CC;
            int lb   = (dh*20 + (jj + dw))*3;          // dj = jj+dw
            int kb   = ((dh*5 + dw)*CC)*FF + f;
            #pragma unroll
            for (int c = 0; c < CC; ++c) {
                ft += x[base + c] * mker[kb + c*FF];
                st += dlds[lb + c] * wker[kb + c*FF];
            }
        }
    }
    out[(((b*HH + i)*WW + j)*FF) + f] = ft - st;
}

extern "C" void kernel_launch(void* const* d_in, const int* in_sizes, int n_in,
                              void* d_out, int out_size, void* d_ws, size_t ws_size,
                              hipStream_t stream) {
    const float* x  = (const float*)d_in[0];   // inputs [2,32,32,3]
    const float* mk = (const float*)d_in[1];   // m [5,5,3,16]
    const float* wk = (const float*)d_in[2];   // w [5,5,3,16]
    const float* gk = (const float*)d_in[3];   // g [5,5,3,16]
    float* out  = (float*)d_out;
    float* part = (float*)d_ws;                // [NCHUNKS][B][M_PER_B] = 1.5 MB

    // No memset needed: every part[] slot is written by diff_kernel before
    // out_kernel reads it (grid covers all (nc,b,mb) exactly once).
    diff_kernel<<<dim3(MBLOCKS, NCHUNKS, BB), 256, 0, stream>>>(x, gk, part);
    out_kernel<<<(BB*HH*2), 256, 0, stream>>>(x, mk, wk, part, out);
}